// Round 5
// baseline (300.463 us; speedup 1.0000x reference)
//
#include <hip/hip_runtime.h>
#include <hip/hip_bf16.h>
#include <math.h>

#define NTOK 32768
#define MCB  4096
#define DDIM 256
#define NGATHER 8192   // gather blocks (4 rows each)

typedef __attribute__((ext_vector_type(8))) short bf16x8;
typedef __attribute__((ext_vector_type(4))) float f32x4;

__device__ __forceinline__ unsigned short f2bf_rne(float f) {
  unsigned int u = __float_as_uint(f);
  unsigned int r = u + 0x7FFFu + ((u >> 16) & 1u);
  return (unsigned short)(r >> 16);
}

__device__ __forceinline__ float bf2f(unsigned short h) {
  return __uint_as_float(((unsigned int)h) << 16);
}

__device__ __forceinline__ void cvt8(const float* f, bf16x8& hi, bf16x8& lo) {
  #pragma unroll
  for (int j = 0; j < 8; ++j) {
    unsigned short hs = f2bf_rne(f[j]);
    float lf = f[j] - bf2f(hs);
    hi[j] = (short)hs;
    lo[j] = (short)f2bf_rne(lf);
  }
}

__device__ __forceinline__ void load_lds16(const void* g, void* l) {
  __builtin_amdgcn_global_load_lds(
      (const __attribute__((address_space(1))) void*)g,
      (__attribute__((address_space(3))) void*)l, 16, 0, 0);
}

// ---------------------------------------------------------------------------
// Prep: embed fp32 -> bf16 hi/lo, PRE-SWIZZLED chunk layout (chunk c of row r
// stored at position c^(r&7)); fused e2[m] = sum_k embed[m][k]^2.
// ---------------------------------------------------------------------------
__global__ __launch_bounds__(256) void vq_prep_kernel(
    const float* __restrict__ embed, char* __restrict__ ehi,
    char* __restrict__ elo, float* __restrict__ e2) {
  const int id = blockIdx.x * 256 + threadIdx.x;
  const int row = id >> 5;
  const int c = id & 31;
  const float* ep = embed + (size_t)row * DDIM + c * 8;
  const float4 f0 = *(const float4*)(ep);
  const float4 f1 = *(const float4*)(ep + 4);
  float f[8] = {f0.x, f0.y, f0.z, f0.w, f1.x, f1.y, f1.z, f1.w};
  bf16x8 h, l;
  cvt8(f, h, l);
  const size_t off = (size_t)row * 512 + (size_t)(((c ^ (row & 7)) * 16));
  *(bf16x8*)(ehi + off) = h;
  *(bf16x8*)(elo + off) = l;
  float s = 0.0f;
  #pragma unroll
  for (int j = 0; j < 8; ++j) s += f[j] * f[j];
  #pragma unroll
  for (int m = 1; m < 32; m <<= 1) s += __shfl_xor(s, m, 64);
  if (c == 0) e2[row] = s;
}

// ---------------------------------------------------------------------------
// Main fused split-bf16 GEMM + running argmin.
// Round-4 change: rf=4 (64 rows/wave, 256 rows/block). B-LDS bytes per FLOP
// halve (B reads amortized over 2x rows held in A registers). ~330 VGPR ->
// 1 wave/SIMD, 1 block/CU; 2-phase dbuf pipeline unchanged.
// ---------------------------------------------------------------------------
__global__ __launch_bounds__(256, 1) void vq_main_kernel(
    const float* __restrict__ x, const char* __restrict__ ehi,
    const char* __restrict__ elo, const float* __restrict__ e2,
    float* __restrict__ ws_score, int* __restrict__ ws_idx) {
  // buf c: hi tile [32 rows][512B] @ c*32768, lo @ c*32768+16384
  __shared__ char lds[65536];
  const int tid = threadIdx.x;
  const int lane = tid & 63;
  const int wv = tid >> 6;
  const int split = blockIdx.x;
  const int row0 = blockIdx.y * 256 + wv * 64;
  const int colbase = split * 1024;
  const int l15 = lane & 15;
  const int l4 = lane >> 4;

  // A (x) fragments for full K, split hi/lo: 4 rowfrags x 8 ksteps (256 VGPR)
  bf16x8 axh[4][8], axl[4][8];
  #pragma unroll
  for (int rf = 0; rf < 4; ++rf) {
    const float* xp = x + (size_t)(row0 + rf * 16 + l15) * DDIM + l4 * 8;
    #pragma unroll
    for (int ks = 0; ks < 8; ++ks) {
      float4 f0 = *(const float4*)(xp + ks * 32);
      float4 f1 = *(const float4*)(xp + ks * 32 + 4);
      float f[8] = {f0.x, f0.y, f0.z, f0.w, f1.x, f1.y, f1.z, f1.w};
      cvt8(f, axh[rf][ks], axl[rf][ks]);
    }
  }

  float minv[4][4];
  int mini[4][4];
  #pragma unroll
  for (int rf = 0; rf < 4; ++rf)
    #pragma unroll
    for (int r = 0; r < 4; ++r) { minv[rf][r] = 3.0e38f; mini[rf][r] = 0; }

  // stage a 32-col tile (16KB hi + 16KB lo) into buffer c
  auto stage = [&](int ct, int c) {
    const size_t tb = (size_t)(colbase + ct * 32) * 512 + (size_t)tid * 16;
    const char* ghi = ehi + tb;
    const char* glo = elo + tb;
    char* dst = lds + c * 32768 + tid * 16;
    #pragma unroll
    for (int i = 0; i < 4; ++i) {
      load_lds16(ghi + i * 4096, dst + i * 4096);
      load_lds16(glo + i * 4096, dst + 16384 + i * 4096);
    }
  };

  stage(0, 0);
  __syncthreads();  // compiler emits vmcnt(0) drain before barrier

  for (int ct = 0; ct < 32; ++ct) {
    const int cur = ct & 1;
    // issue next tile's staging FIRST -- overlaps with compute below
    if (ct < 31) stage(ct + 1, cur ^ 1);

    const char* base = lds + cur * 32768;
    f32x4 acc[4][2];
    #pragma unroll
    for (int rf = 0; rf < 4; ++rf)
      #pragma unroll
      for (int cf = 0; cf < 2; ++cf) {
        f32x4 z = {0.0f, 0.0f, 0.0f, 0.0f};
        acc[rf][cf] = z;
      }

    #pragma unroll
    for (int ks = 0; ks < 8; ++ks) {
      bf16x8 bh[2], bl[2];
      #pragma unroll
      for (int cf = 0; cf < 2; ++cf) {
        const int brow = cf * 16 + l15;
        const int off = brow * 512 + (((ks * 4 + l4) ^ (brow & 7)) * 16);
        bh[cf] = *(const bf16x8*)(base + off);
        bl[cf] = *(const bf16x8*)(base + 16384 + off);
      }
      #pragma unroll
      for (int rf = 0; rf < 4; ++rf)
        #pragma unroll
        for (int cf = 0; cf < 2; ++cf) {
          f32x4 a = acc[rf][cf];
          a = __builtin_amdgcn_mfma_f32_16x16x32_bf16(axh[rf][ks], bh[cf], a, 0, 0, 0);
          a = __builtin_amdgcn_mfma_f32_16x16x32_bf16(axh[rf][ks], bl[cf], a, 0, 0, 0);
          a = __builtin_amdgcn_mfma_f32_16x16x32_bf16(axl[rf][ks], bh[cf], a, 0, 0, 0);
          acc[rf][cf] = a;
        }
    }

    // score = e2[col] - 2*dot ; running argmin (cols increase -> strict < keeps first)
    #pragma unroll
    for (int cf = 0; cf < 2; ++cf) {
      const int col = colbase + ct * 32 + cf * 16 + l15;
      const float ee = e2[col];
      #pragma unroll
      for (int rf = 0; rf < 4; ++rf)
        #pragma unroll
        for (int r = 0; r < 4; ++r) {
          const float s = fmaf(-2.0f, acc[rf][cf][r], ee);
          if (s < minv[rf][r]) { minv[rf][r] = s; mini[rf][r] = col; }
        }
    }

    __syncthreads();  // drains vmcnt(0): next tile ready; cur free to overwrite
  }

  // cross-lane (16 lanes share a row) lexicographic argmin reduce
  #pragma unroll
  for (int rf = 0; rf < 4; ++rf)
    #pragma unroll
    for (int r = 0; r < 4; ++r) {
      float s = minv[rf][r];
      int c = mini[rf][r];
      #pragma unroll
      for (int m = 1; m < 16; m <<= 1) {
        const float os = __shfl_xor(s, m, 64);
        const int oc = __shfl_xor(c, m, 64);
        if (os < s || (os == s && oc < c)) { s = os; c = oc; }
      }
      if (l15 == 0) {
        const int row = row0 + rf * 16 + l4 * 4 + r;
        ws_score[row * 4 + split] = s;
        ws_idx[row * 4 + split] = c;
      }
    }
}

// ---------------------------------------------------------------------------
// Merge 4 col-splits per row -> final idx; histogram; idx-as-float output
// ---------------------------------------------------------------------------
__global__ void vq_merge_kernel(const float* __restrict__ ws_score,
                                const int* __restrict__ ws_idx,
                                int* __restrict__ minidx,
                                float* __restrict__ counts,
                                float* __restrict__ out_idx) {
  const int row = blockIdx.x * 256 + threadIdx.x;
  float bs = ws_score[row * 4];
  int bc = ws_idx[row * 4];
  #pragma unroll
  for (int s2 = 1; s2 < 4; ++s2) {
    const float s = ws_score[row * 4 + s2];
    const int c = ws_idx[row * 4 + s2];
    if (s < bs || (s == bs && c < bc)) { bs = s; bc = c; }
  }
  minidx[row] = bc;
  out_idx[row] = (float)bc;
  atomicAdd(&counts[bc], 1.0f);
}

// ---------------------------------------------------------------------------
// Gather quantized = x + (q - x); per-block fp64 partial of sum((q-x)^2).
// ---------------------------------------------------------------------------
__global__ __launch_bounds__(256) void vq_gather_kernel(
    const float* __restrict__ x, const float* __restrict__ embed,
    const int* __restrict__ minidx, float* __restrict__ outq,
    double* __restrict__ partials) {
  __shared__ double sh[4];
  const int lane = threadIdx.x & 63;
  const int wv = threadIdx.x >> 6;
  const int row = blockIdx.x * 4 + wv;
  const int idx = minidx[row];
  const float4 q4 = *(const float4*)(embed + (size_t)idx * DDIM + lane * 4);
  const float4 x4 = *(const float4*)(x + (size_t)row * DDIM + lane * 4);
  const float dx = q4.x - x4.x, dy = q4.y - x4.y, dz = q4.z - x4.z, dw = q4.w - x4.w;
  float4 o;
  o.x = x4.x + dx; o.y = x4.y + dy; o.z = x4.z + dz; o.w = x4.w + dw;
  *(float4*)(outq + (size_t)row * DDIM + lane * 4) = o;
  double ss = (double)(dx * dx) + (double)(dy * dy) + (double)(dz * dz) + (double)(dw * dw);
  #pragma unroll
  for (int m = 1; m < 64; m <<= 1) ss += __shfl_xor(ss, m, 64);
  if (lane == 0) sh[wv] = ss;
  __syncthreads();
  if (threadIdx.x == 0) partials[blockIdx.x] = sh[0] + sh[1] + sh[2] + sh[3];
}

// ---------------------------------------------------------------------------
// Finalize: sum loss partials + entropy -> loss scalar + perplexity
// ---------------------------------------------------------------------------
__global__ void vq_fin_kernel(const float* __restrict__ counts,
                              const double* __restrict__ partials,
                              float* __restrict__ out) {
  __shared__ double sh[256];
  __shared__ double sl[256];
  double h = 0.0;
  for (int i = threadIdx.x; i < MCB; i += 256) {
    const float p = counts[i] * (1.0f / 32768.0f);
    h += (double)(p * logf(p + 1e-10f));
  }
  double ls = 0.0;
  for (int i = threadIdx.x; i < NGATHER; i += 256) ls += partials[i];
  sh[threadIdx.x] = h;
  sl[threadIdx.x] = ls;
  __syncthreads();
  for (int s = 128; s > 0; s >>= 1) {
    if (threadIdx.x < s) {
      sh[threadIdx.x] += sh[threadIdx.x + s];
      sl[threadIdx.x] += sl[threadIdx.x + s];
    }
    __syncthreads();
  }
  if (threadIdx.x == 0) {
    const size_t base = (size_t)NTOK * DDIM + NTOK;
    out[base] = (float)(1.25 * sl[0] / (double)((size_t)NTOK * DDIM));
    out[base + 1] = (float)exp(-sh[0]);
  }
}

extern "C" void kernel_launch(void* const* d_in, const int* in_sizes, int n_in,
                              void* d_out, int out_size, void* d_ws, size_t ws_size,
                              hipStream_t stream) {
  const float* x = (const float*)d_in[0];
  const float* embed = (const float*)d_in[1];
  float* out = (float*)d_out;
  char* ws = (char*)d_ws;

  float* ws_score = (float*)(ws);                 // N*4 floats   @ 0x000000
  int* ws_idx = (int*)(ws + 0x80000);             // N*4 ints     @ 0x080000
  int* minidx = (int*)(ws + 0x100000);            // N ints       @ 0x100000
  float* counts = (float*)(ws + 0x120000);        // M floats     @ 0x120000
  double* partials = (double*)(ws + 0x128000);    // 8192 doubles @ 0x128000 (64KB)
  float* e2 = (float*)(ws + 0x138000);            // M floats     @ 0x138000
  char* ehi = ws + 0x140000;                      // M*512 B      @ 0x140000 (2MB)
  char* elo = ws + 0x340000;                      // M*512 B      @ 0x340000 (2MB)

  hipMemsetAsync(ws + 0x120000, 0, 16384, stream);  // counts
  hipLaunchKernelGGL(vq_prep_kernel, dim3(512), dim3(256), 0, stream,
                     embed, ehi, elo, e2);
  hipLaunchKernelGGL(vq_main_kernel, dim3(4, 128), dim3(256), 0, stream,
                     x, ehi, elo, e2, ws_score, ws_idx);
  hipLaunchKernelGGL(vq_merge_kernel, dim3(128), dim3(256), 0, stream,
                     ws_score, ws_idx, minidx, counts, out + (size_t)NTOK * DDIM);
  hipLaunchKernelGGL(vq_gather_kernel, dim3(NGATHER), dim3(256), 0, stream,
                     x, embed, minidx, out, partials);
  hipLaunchKernelGGL(vq_fin_kernel, dim3(1), dim3(256), 0, stream,
                     counts, partials, out);
}

// Round 7
// 275.186 us; speedup vs baseline: 1.0919x; 1.0919x over previous
//
#include <hip/hip_runtime.h>
#include <hip/hip_bf16.h>
#include <math.h>

#define NTOK 32768
#define MCB  4096
#define DDIM 256
#define NGATHER 8192   // gather blocks (4 rows each)

typedef __attribute__((ext_vector_type(8))) short bf16x8;
typedef __attribute__((ext_vector_type(4))) float f32x4;

template<int V> struct ic { static constexpr int v = V; };

__device__ __forceinline__ unsigned short f2bf_rne(float f) {
  unsigned int u = __float_as_uint(f);
  unsigned int r = u + 0x7FFFu + ((u >> 16) & 1u);
  return (unsigned short)(r >> 16);
}

__device__ __forceinline__ float bf2f(unsigned short h) {
  return __uint_as_float(((unsigned int)h) << 16);
}

__device__ __forceinline__ void cvt8(const float* f, bf16x8& hi, bf16x8& lo) {
  #pragma unroll
  for (int j = 0; j < 8; ++j) {
    unsigned short hs = f2bf_rne(f[j]);
    float lf = f[j] - bf2f(hs);
    hi[j] = (short)hs;
    lo[j] = (short)f2bf_rne(lf);
  }
}

__device__ __forceinline__ void load_lds16(const void* g, void* l) {
  __builtin_amdgcn_global_load_lds(
      (const __attribute__((address_space(1))) void*)g,
      (__attribute__((address_space(3))) void*)l, 16, 0, 0);
}

// ---------------------------------------------------------------------------
// Prep: embed fp32 -> bf16 hi/lo, PRE-SWIZZLED chunk layout (chunk c of row r
// stored at position c^(r&7)); fused e2[m] = sum_k embed[m][k]^2.
// ---------------------------------------------------------------------------
__global__ __launch_bounds__(256) void vq_prep_kernel(
    const float* __restrict__ embed, char* __restrict__ ehi,
    char* __restrict__ elo, float* __restrict__ e2) {
  const int id = blockIdx.x * 256 + threadIdx.x;
  const int row = id >> 5;
  const int c = id & 31;
  const float* ep = embed + (size_t)row * DDIM + c * 8;
  const float4 f0 = *(const float4*)(ep);
  const float4 f1 = *(const float4*)(ep + 4);
  float f[8] = {f0.x, f0.y, f0.z, f0.w, f1.x, f1.y, f1.z, f1.w};
  bf16x8 h, l;
  cvt8(f, h, l);
  const size_t off = (size_t)row * 512 + (size_t)(((c ^ (row & 7)) * 16));
  *(bf16x8*)(ehi + off) = h;
  *(bf16x8*)(elo + off) = l;
  float s = 0.0f;
  #pragma unroll
  for (int j = 0; j < 8; ++j) s += f[j] * f[j];
  #pragma unroll
  for (int m = 1; m < 32; m <<= 1) s += __shfl_xor(s, m, 64);
  if (c == 0) e2[row] = s;
}

// ---------------------------------------------------------------------------
// Main fused split-bf16 GEMM + running argmin. rf=2 (round-4 winner) plus:
//  - e2 staged to LDS once (main loop has ZERO non-stage VMEM -> counted
//    vmcnt works; no FIFO drain at argmin)
//  - raw s_barrier + s_waitcnt vmcnt(8) (never 0 in steady state; m201/m218)
//  - ds_read addresses: 2 VGPR bases + compile-time immediates only
//    (XOR swizzle split: chunk = (l4^(r&3)) + 4*((ks&1)^b) + 8*(ks>>1))
//  - T5 setprio(1) around MFMA cluster (2 independent blocks/CU)
// ---------------------------------------------------------------------------
__global__ __launch_bounds__(256, 2) void vq_main_kernel(
    const float* __restrict__ x, const char* __restrict__ ehi,
    const char* __restrict__ elo, const float* __restrict__ e2,
    float* __restrict__ ws_score, int* __restrict__ ws_idx) {
  // buf P at P*32768: hi tile [32 rows][512B] @ +0, lo @ +16384
  __shared__ char lds[65536];
  __shared__ float e2s[1024];
  const int tid = threadIdx.x;
  const int lane = tid & 63;
  const int wv = tid >> 6;
  const int split = blockIdx.x;
  const int row0 = blockIdx.y * 128 + wv * 32;
  const int colbase = split * 1024;
  const int l15 = lane & 15;
  const int l4 = lane >> 4;

  // A (x) fragments for full K, split hi/lo: 2 rowfrags x 8 ksteps
  bf16x8 axh[2][8], axl[2][8];
  #pragma unroll
  for (int rf = 0; rf < 2; ++rf) {
    const float* xp = x + (size_t)(row0 + rf * 16 + l15) * DDIM + l4 * 8;
    #pragma unroll
    for (int ks = 0; ks < 8; ++ks) {
      float4 f0 = *(const float4*)(xp + ks * 32);
      float4 f1 = *(const float4*)(xp + ks * 32 + 4);
      float f[8] = {f0.x, f0.y, f0.z, f0.w, f1.x, f1.y, f1.z, f1.w};
      cvt8(f, axh[rf][ks], axl[rf][ks]);
    }
  }

  // e2 for this split -> LDS (1024 floats)
  *(float4*)&e2s[tid * 4] = *(const float4*)&e2[colbase + tid * 4];

  float minv[2][4];
  int mini[2][4];
  #pragma unroll
  for (int rf = 0; rf < 2; ++rf)
    #pragma unroll
    for (int r = 0; r < 4; ++r) { minv[rf][r] = 3.0e38f; mini[rf][r] = 0; }

  // ds_read bases: all 32 reads/tile = {pe|po} + immediate
  const int r3 = l15 & 3;
  const int b = (l15 >> 2) & 1;
  const int Veven = l15 * 512 + (l4 ^ r3) * 16 + b * 64;
  const char* pe = &lds[Veven];
  const char* po = &lds[Veven + 64 - b * 128];

  // staging bases
  const char* gh = ehi + (size_t)colbase * 512 + tid * 16;
  const char* gl = elo + (size_t)colbase * 512 + tid * 16;
  char* dst0 = &lds[tid * 16];

  auto stage = [&](int ct, int c) {
    const char* sh_ = gh + ct * 16384;
    const char* sl_ = gl + ct * 16384;
    char* d = dst0 + c * 32768;
    #pragma unroll
    for (int i = 0; i < 4; ++i) {
      load_lds16(sh_ + i * 4096, d + i * 4096);
      load_lds16(sl_ + i * 4096, d + 16384 + i * 4096);
    }
  };

  auto body = [&](auto pc, int t) {
    constexpr int P = decltype(pc)::v * 32768;
    const float ee0 = e2s[t * 32 + l15];        // lgkm-domain, no vmcnt
    const float ee1 = e2s[t * 32 + 16 + l15];
    f32x4 acc[2][2];
    #pragma unroll
    for (int rf = 0; rf < 2; ++rf)
      #pragma unroll
      for (int cf = 0; cf < 2; ++cf) {
        f32x4 z = {0.0f, 0.0f, 0.0f, 0.0f};
        acc[rf][cf] = z;
      }
    __builtin_amdgcn_s_setprio(1);
    #pragma unroll
    for (int ks = 0; ks < 8; ++ks) {
      const char* pb = (ks & 1) ? po : pe;      // folds after unroll
      const int kimm = P + (ks >> 1) * 128;
      bf16x8 bh0 = *(const bf16x8*)(pb + kimm);
      bf16x8 bh1 = *(const bf16x8*)(pb + kimm + 8192);
      bf16x8 bl0 = *(const bf16x8*)(pb + kimm + 16384);
      bf16x8 bl1 = *(const bf16x8*)(pb + kimm + 24576);
      #pragma unroll
      for (int rf = 0; rf < 2; ++rf) {
        f32x4 a0 = acc[rf][0];
        a0 = __builtin_amdgcn_mfma_f32_16x16x32_bf16(axh[rf][ks], bh0, a0, 0, 0, 0);
        a0 = __builtin_amdgcn_mfma_f32_16x16x32_bf16(axh[rf][ks], bl0, a0, 0, 0, 0);
        a0 = __builtin_amdgcn_mfma_f32_16x16x32_bf16(axl[rf][ks], bh0, a0, 0, 0, 0);
        acc[rf][0] = a0;
        f32x4 a1 = acc[rf][1];
        a1 = __builtin_amdgcn_mfma_f32_16x16x32_bf16(axh[rf][ks], bh1, a1, 0, 0, 0);
        a1 = __builtin_amdgcn_mfma_f32_16x16x32_bf16(axh[rf][ks], bl1, a1, 0, 0, 0);
        a1 = __builtin_amdgcn_mfma_f32_16x16x32_bf16(axl[rf][ks], bh1, a1, 0, 0, 0);
        acc[rf][1] = a1;
      }
    }
    __builtin_amdgcn_s_setprio(0);
    // score = e2[col] - 2*dot ; running argmin (strict < keeps first index)
    #pragma unroll
    for (int cf = 0; cf < 2; ++cf) {
      const int col = colbase + t * 32 + cf * 16 + l15;
      const float ee = cf ? ee1 : ee0;
      #pragma unroll
      for (int rf = 0; rf < 2; ++rf)
        #pragma unroll
        for (int r = 0; r < 4; ++r) {
          const float s = fmaf(-2.0f, acc[rf][cf][r], ee);
          if (s < minv[rf][r]) { minv[rf][r] = s; mini[rf][r] = col; }
        }
    }
  };

  stage(0, 0);
  __syncthreads();   // prologue: full drain (tile0 + e2s visible)
  stage(1, 1);       // 8 loads in flight entering the loop

  for (int t = 0; t < 32; t += 2) {
    body(ic<0>{}, t);
    __builtin_amdgcn_s_barrier();             // all waves done reading buf0
    if (t < 30) {
      stage(t + 2, 0);                        // 16 in flight
      asm volatile("s_waitcnt vmcnt(8)" ::: "memory");  // t+1 landed
    } else {
      asm volatile("s_waitcnt vmcnt(0)" ::: "memory");
    }
    __builtin_amdgcn_sched_barrier(0);
    __builtin_amdgcn_s_barrier();             // collectively landed
    __builtin_amdgcn_sched_barrier(0);
    body(ic<1>{}, t + 1);
    if (t < 30) {
      __builtin_amdgcn_s_barrier();
      if (t < 29) {
        stage(t + 3, 1);
        asm volatile("s_waitcnt vmcnt(8)" ::: "memory");
      } else {
        asm volatile("s_waitcnt vmcnt(0)" ::: "memory");
      }
      __builtin_amdgcn_sched_barrier(0);
      __builtin_amdgcn_s_barrier();
      __builtin_amdgcn_sched_barrier(0);
    }
  }

  // cross-lane (16 lanes share a row) lexicographic argmin reduce
  #pragma unroll
  for (int rf = 0; rf < 2; ++rf)
    #pragma unroll
    for (int r = 0; r < 4; ++r) {
      float s = minv[rf][r];
      int c = mini[rf][r];
      #pragma unroll
      for (int m = 1; m < 16; m <<= 1) {
        const float os = __shfl_xor(s, m, 64);
        const int oc = __shfl_xor(c, m, 64);
        if (os < s || (os == s && oc < c)) { s = os; c = oc; }
      }
      if (l15 == 0) {
        const int row = row0 + rf * 16 + l4 * 4 + r;
        ws_score[row * 4 + split] = s;
        ws_idx[row * 4 + split] = c;
      }
    }
}

// ---------------------------------------------------------------------------
// Merge 4 col-splits per row -> final idx; histogram; idx-as-float output
// ---------------------------------------------------------------------------
__global__ void vq_merge_kernel(const float* __restrict__ ws_score,
                                const int* __restrict__ ws_idx,
                                int* __restrict__ minidx,
                                float* __restrict__ counts,
                                float* __restrict__ out_idx) {
  const int row = blockIdx.x * 256 + threadIdx.x;
  float bs = ws_score[row * 4];
  int bc = ws_idx[row * 4];
  #pragma unroll
  for (int s2 = 1; s2 < 4; ++s2) {
    const float s = ws_score[row * 4 + s2];
    const int c = ws_idx[row * 4 + s2];
    if (s < bs || (s == bs && c < bc)) { bs = s; bc = c; }
  }
  minidx[row] = bc;
  out_idx[row] = (float)bc;
  atomicAdd(&counts[bc], 1.0f);
}

// ---------------------------------------------------------------------------
// Gather quantized = x + (q - x); per-block fp64 partial of sum((q-x)^2).
// ---------------------------------------------------------------------------
__global__ __launch_bounds__(256) void vq_gather_kernel(
    const float* __restrict__ x, const float* __restrict__ embed,
    const int* __restrict__ minidx, float* __restrict__ outq,
    double* __restrict__ partials) {
  __shared__ double sh[4];
  const int lane = threadIdx.x & 63;
  const int wv = threadIdx.x >> 6;
  const int row = blockIdx.x * 4 + wv;
  const int idx = minidx[row];
  const float4 q4 = *(const float4*)(embed + (size_t)idx * DDIM + lane * 4);
  const float4 x4 = *(const float4*)(x + (size_t)row * DDIM + lane * 4);
  const float dx = q4.x - x4.x, dy = q4.y - x4.y, dz = q4.z - x4.z, dw = q4.w - x4.w;
  float4 o;
  o.x = x4.x + dx; o.y = x4.y + dy; o.z = x4.z + dz; o.w = x4.w + dw;
  *(float4*)(outq + (size_t)row * DDIM + lane * 4) = o;
  double ss = (double)(dx * dx) + (double)(dy * dy) + (double)(dz * dz) + (double)(dw * dw);
  #pragma unroll
  for (int m = 1; m < 64; m <<= 1) ss += __shfl_xor(ss, m, 64);
  if (lane == 0) sh[wv] = ss;
  __syncthreads();
  if (threadIdx.x == 0) partials[blockIdx.x] = sh[0] + sh[1] + sh[2] + sh[3];
}

// ---------------------------------------------------------------------------
// Finalize: sum loss partials + entropy -> loss scalar + perplexity
// ---------------------------------------------------------------------------
__global__ void vq_fin_kernel(const float* __restrict__ counts,
                              const double* __restrict__ partials,
                              float* __restrict__ out) {
  __shared__ double sh[256];
  __shared__ double sl[256];
  double h = 0.0;
  for (int i = threadIdx.x; i < MCB; i += 256) {
    const float p = counts[i] * (1.0f / 32768.0f);
    h += (double)(p * logf(p + 1e-10f));
  }
  double ls = 0.0;
  for (int i = threadIdx.x; i < NGATHER; i += 256) ls += partials[i];
  sh[threadIdx.x] = h;
  sl[threadIdx.x] = ls;
  __syncthreads();
  for (int s = 128; s > 0; s >>= 1) {
    if (threadIdx.x < s) {
      sh[threadIdx.x] += sh[threadIdx.x + s];
      sl[threadIdx.x] += sl[threadIdx.x + s];
    }
    __syncthreads();
  }
  if (threadIdx.x == 0) {
    const size_t base = (size_t)NTOK * DDIM + NTOK;
    out[base] = (float)(1.25 * sl[0] / (double)((size_t)NTOK * DDIM));
    out[base + 1] = (float)exp(-sh[0]);
  }
}

extern "C" void kernel_launch(void* const* d_in, const int* in_sizes, int n_in,
                              void* d_out, int out_size, void* d_ws, size_t ws_size,
                              hipStream_t stream) {
  const float* x = (const float*)d_in[0];
  const float* embed = (const float*)d_in[1];
  float* out = (float*)d_out;
  char* ws = (char*)d_ws;

  float* ws_score = (float*)(ws);                 // N*4 floats   @ 0x000000
  int* ws_idx = (int*)(ws + 0x80000);             // N*4 ints     @ 0x080000
  int* minidx = (int*)(ws + 0x100000);            // N ints       @ 0x100000
  float* counts = (float*)(ws + 0x120000);        // M floats     @ 0x120000
  double* partials = (double*)(ws + 0x128000);    // 8192 doubles @ 0x128000 (64KB)
  float* e2 = (float*)(ws + 0x138000);            // M floats     @ 0x138000
  char* ehi = ws + 0x140000;                      // M*512 B      @ 0x140000 (2MB)
  char* elo = ws + 0x340000;                      // M*512 B      @ 0x340000 (2MB)

  hipMemsetAsync(ws + 0x120000, 0, 16384, stream);  // counts
  hipLaunchKernelGGL(vq_prep_kernel, dim3(512), dim3(256), 0, stream,
                     embed, ehi, elo, e2);
  hipLaunchKernelGGL(vq_main_kernel, dim3(4, 256), dim3(256), 0, stream,
                     x, ehi, elo, e2, ws_score, ws_idx);
  hipLaunchKernelGGL(vq_merge_kernel, dim3(128), dim3(256), 0, stream,
                     ws_score, ws_idx, minidx, counts, out + (size_t)NTOK * DDIM);
  hipLaunchKernelGGL(vq_gather_kernel, dim3(NGATHER), dim3(256), 0, stream,
                     x, embed, minidx, out, partials);
  hipLaunchKernelGGL(vq_fin_kernel, dim3(1), dim3(256), 0, stream,
                     counts, partials, out);
}